// Round 1
// baseline (97.224 us; speedup 1.0000x reference)
//
#include <hip/hip_runtime.h>

#define KA 50
#define KP 52
#define FDIM 6
#define H 128
#define D 256
#define NBLK 256
#define BLOCK 512
#define RPT 13   // ceil(50/4) rows per bg-group thread

__device__ __forceinline__ float bf2f(unsigned short u) {
  return __uint_as_float(((unsigned)u) << 16);
}
__device__ __forceinline__ unsigned short f2bf(float f) {
  unsigned u = __float_as_uint(f);
  u = (u + 0x7FFFu + ((u >> 16) & 1u)) >> 16;   // RNE bf16
  return (unsigned short)u;
}

struct Smem {
  float s[KA][FDIM];       // raw states (pos, vel exact fp32)
  float m[KA];
  float cnta[KA];
  float invden[KA];
  float geo[2][KP][4];     // dist, angle, speed_diff for 2 a-rows
  float red[1024];         // cross-bg reduction scratch (also [2][256] later)
  float pooled[H];
  float latent1[D];
  float cnt;
  unsigned short af[KP][H];   // agent_feat, bf16
  unsigned short xi[KP][H];   // x_i, bf16; reused as agg after pair phase
  float hsum[KP][H];          // masked relu-sum over b, fp32
};

__global__ void __launch_bounds__(BLOCK) rpe_kernel(
    const float* __restrict__ states, const float* __restrict__ masks,
    const float* __restrict__ w_a,  const float* __restrict__ b_a,
    const float* __restrict__ w_r1, const float* __restrict__ b_r1,
    const float* __restrict__ w_r2, const float* __restrict__ b_r2,
    const float* __restrict__ w_g,  const float* __restrict__ b_g,
    const float* __restrict__ w_f1, const float* __restrict__ b_f1,
    const float* __restrict__ w_f2, const float* __restrict__ b_f2,
    float* __restrict__ out) {
  __shared__ Smem sh;
  const int n = blockIdx.x;
  const int tid = threadIdx.x;
  const int c = tid & (H - 1);
  const int bg = tid >> 7;   // 0..3

  // ---------------- Phase 0: stage states, masks; zero pad rows ----------
  {
    const float* sp = states + (size_t)n * (KA * FDIM);
    for (int i = tid; i < KA * FDIM; i += BLOCK) (&sh.s[0][0])[i] = sp[i];
    if (tid < KA) sh.m[tid] = masks[(size_t)n * KA + tid];
    if (tid < 2 * H) {
      const int rr = KA + (tid >> 7), cc = tid & (H - 1);
      sh.af[rr][cc] = 0; sh.xi[rr][cc] = 0; sh.hsum[rr][cc] = 0.f;
    }
  }
  __syncthreads();
  if (tid == 0) {
    float csum = 0.f;
    for (int b = 0; b < KA; ++b) csum += sh.m[b];
    sh.cnt = csum;
  }
  // ---------------- Phase 1: agent_feat = relu(s @ w_a + b_a) ------------
  {
    const float bac = b_a[c];
    const float w0 = w_a[0*H+c], w1 = w_a[1*H+c], w2 = w_a[2*H+c];
    const float w3 = w_a[3*H+c], w4 = w_a[4*H+c], w5 = w_a[5*H+c];
    #pragma unroll
    for (int r = 0; r < RPT; ++r) {
      const int a = bg + 4*r;
      if (a < KA) {
        const float* srow = sh.s[a];
        float v = fmaf(srow[0], w0, fmaf(srow[1], w1, fmaf(srow[2], w2,
                  fmaf(srow[3], w3, fmaf(srow[4], w4, fmaf(srow[5], w5, bac))))));
        sh.af[a][c] = f2bf(fmaxf(v, 0.f));
      }
    }
  }
  __syncthreads();
  if (tid < KA) {
    const float ca = sh.m[tid] * sh.cnt;       // sum_b mask_pairs for row a
    sh.cnta[tid] = ca;
    sh.invden[tid] = 1.0f / fmaxf(ca, 1.0f);
  }

  // ---------------- Phase 2: xi -> LDS; xj stays in registers ------------
  // thread (bg,c) computes rows a = bg+4r; those same rows are exactly its
  // b-subset in the pair loop, so accj == xj[b][c] carries over directly.
  float xjv[RPT], mb[RPT];
  {
    float acci[RPT];
    #pragma unroll
    for (int r = 0; r < RPT; ++r) { acci[r] = 0.f; xjv[r] = 0.f; }
    const float* wi = w_r1 + c;            // rows 0..127
    const float* wj = w_r1 + H * H + c;    // rows 128..255
    for (int k = 0; k < H; k += 4) {
      const float wi0 = wi[(k+0)*H], wi1 = wi[(k+1)*H], wi2 = wi[(k+2)*H], wi3 = wi[(k+3)*H];
      const float wj0 = wj[(k+0)*H], wj1 = wj[(k+1)*H], wj2 = wj[(k+2)*H], wj3 = wj[(k+3)*H];
      #pragma unroll
      for (int r = 0; r < RPT; ++r) {
        const int a = bg + 4*r;            // pad rows are zero -> harmless
        const ushort4 p = *reinterpret_cast<const ushort4*>(&sh.af[a][k]);
        const float f0 = bf2f(p.x), f1 = bf2f(p.y), f2v = bf2f(p.z), f3 = bf2f(p.w);
        acci[r] = fmaf(f0, wi0, acci[r]); acci[r] = fmaf(f1, wi1, acci[r]);
        acci[r] = fmaf(f2v, wi2, acci[r]); acci[r] = fmaf(f3, wi3, acci[r]);
        xjv[r]  = fmaf(f0, wj0, xjv[r]);  xjv[r]  = fmaf(f1, wj1, xjv[r]);
        xjv[r]  = fmaf(f2v, wj2, xjv[r]); xjv[r]  = fmaf(f3, wj3, xjv[r]);
      }
    }
    #pragma unroll
    for (int r = 0; r < RPT; ++r) {
      const int a = bg + 4*r;
      if (a < KA) { sh.xi[a][c] = f2bf(acci[r]); mb[r] = sh.m[a]; }
      else        { mb[r] = 0.f; xjv[r] = 0.f; }
    }
  }
  __syncthreads();

  // ---------------- Phase 3: pair loop -> hsum (2 a-rows per iter) -------
  {
    const float wgd  = w_r1[256*H + c];
    const float wgan = w_r1[257*H + c];
    const float wgs  = w_r1[258*H + c];
    const float br1c = b_r1[c];
    for (int a0 = 0; a0 < KA; a0 += 2) {
      if (tid < 128) {                    // stage geo for rows a0, a0+1
        const int ao = tid >> 6;
        const int b  = tid & 63;
        if (b < KA) {
          const int a = a0 + ao;
          const float rx  = sh.s[b][0] - sh.s[a][0];
          const float ry  = sh.s[b][1] - sh.s[a][1];
          const float dvx = sh.s[b][2] - sh.s[a][2];
          const float dvy = sh.s[b][3] - sh.s[a][3];
          const float sq   = fmaf(rx, rx, ry*ry);
          const float dist = (sq == 0.f) ? 0.f : sqrtf(sq);
          const float sx   = (rx == 0.f && ry == 0.f) ? 1.f : rx;
          const float ang  = atan2f(ry, sx);
          const float sq2  = fmaf(dvx, dvx, dvy*dvy);
          const float sd   = (sq2 == 0.f) ? 0.f : sqrtf(sq2);
          float* gg = sh.geo[ao][b];
          gg[0] = dist; gg[1] = ang; gg[2] = sd; gg[3] = 0.f;
        }
      }
      __syncthreads();
      const float ma0 = sh.m[a0], ma1 = sh.m[a0 + 1];
      if (ma0 != 0.f || ma1 != 0.f) {     // wave-uniform skip
        const float xiv0 = bf2f(sh.xi[a0][c]);
        const float xiv1 = bf2f(sh.xi[a0 + 1][c]);
        float hacc0 = 0.f, hacc1 = 0.f;
        #pragma unroll
        for (int r = 0; r < RPT; ++r) {
          const int b = bg + 4*r;
          if (b < KA) {
            const float4 g0 = *reinterpret_cast<const float4*>(sh.geo[0][b]);
            const float4 g1 = *reinterpret_cast<const float4*>(sh.geo[1][b]);
            const float gv0 = fmaf(g0.x, wgd, fmaf(g0.y, wgan, fmaf(g0.z, wgs, br1c)));
            const float gv1 = fmaf(g1.x, wgd, fmaf(g1.y, wgan, fmaf(g1.z, wgs, br1c)));
            const float t = xjv[r];
            hacc0 = fmaf(mb[r], fmaxf(xiv0 + t + gv0, 0.f), hacc0);
            hacc1 = fmaf(mb[r], fmaxf(xiv1 + t + gv1, 0.f), hacc1);
          }
        }
        sh.red[bg * H + c]       = hacc0;
        sh.red[(4 + bg) * H + c] = hacc1;
      }
      __syncthreads();
      if (bg < 2) {
        const int a = a0 + bg;
        float tot = 0.f;
        if (sh.m[a] != 0.f) {
          const float* rr = sh.red + bg * 4 * H;
          tot = (rr[c] + rr[H + c]) + (rr[2*H + c] + rr[3*H + c]);
        }
        sh.hsum[a][c] = tot;   // m[a] factor: rows with m[a]==0 store 0
      }
    }
  }
  __syncthreads();

  // ---------------- Phase 4: agg = (hsum@w_r2 + cnta*b_r2)*invden -> xi --
  {
    float acc[RPT];
    #pragma unroll
    for (int r = 0; r < RPT; ++r) acc[r] = 0.f;
    const float* wr2 = w_r2 + c;
    for (int k = 0; k < H; k += 4) {
      const float w0 = wr2[(k+0)*H], w1 = wr2[(k+1)*H], w2 = wr2[(k+2)*H], w3 = wr2[(k+3)*H];
      #pragma unroll
      for (int r = 0; r < RPT; ++r) {
        const int a = bg + 4*r;
        const float4 hv = *reinterpret_cast<const float4*>(&sh.hsum[a][k]);
        acc[r] = fmaf(hv.x, w0, acc[r]);
        acc[r] = fmaf(hv.y, w1, acc[r]);
        acc[r] = fmaf(hv.z, w2, acc[r]);
        acc[r] = fmaf(hv.w, w3, acc[r]);
      }
    }
    const float br2c = b_r2[c];
    #pragma unroll
    for (int r = 0; r < RPT; ++r) {
      const int a = bg + 4*r;
      if (a < KA) {
        const float v = fmaf(sh.cnta[a], br2c, acc[r]) * sh.invden[a];
        sh.xi[a][c] = f2bf(v);   // xi now holds agg (bf16)
      }
    }
  }
  __syncthreads();

  // ---------------- Phase 5: combined + masked pooling -------------------
  {
    float acc[RPT];
    #pragma unroll
    for (int r = 0; r < RPT; ++r) acc[r] = 0.f;
    const float* wga = w_g + c;            // rows 0..127 (agent_feat part)
    const float* wgb = w_g + H * H + c;    // rows 128..255 (agg part)
    for (int k = 0; k < H; k += 4) {
      const float a0w = wga[(k+0)*H], a1w = wga[(k+1)*H], a2w = wga[(k+2)*H], a3w = wga[(k+3)*H];
      const float b0w = wgb[(k+0)*H], b1w = wgb[(k+1)*H], b2w = wgb[(k+2)*H], b3w = wgb[(k+3)*H];
      #pragma unroll
      for (int r = 0; r < RPT; ++r) {
        const int a = bg + 4*r;
        const ushort4 pa = *reinterpret_cast<const ushort4*>(&sh.af[a][k]);
        const ushort4 pg = *reinterpret_cast<const ushort4*>(&sh.xi[a][k]);
        acc[r] = fmaf(bf2f(pa.x), a0w, acc[r]);
        acc[r] = fmaf(bf2f(pa.y), a1w, acc[r]);
        acc[r] = fmaf(bf2f(pa.z), a2w, acc[r]);
        acc[r] = fmaf(bf2f(pa.w), a3w, acc[r]);
        acc[r] = fmaf(bf2f(pg.x), b0w, acc[r]);
        acc[r] = fmaf(bf2f(pg.y), b1w, acc[r]);
        acc[r] = fmaf(bf2f(pg.z), b2w, acc[r]);
        acc[r] = fmaf(bf2f(pg.w), b3w, acc[r]);
      }
    }
    const float bgc = b_g[c];
    float pp = 0.f;
    #pragma unroll
    for (int r = 0; r < RPT; ++r) {
      const int a = bg + 4*r;
      if (a < KA) pp = fmaf(sh.m[a], fmaxf(acc[r] + bgc, 0.f), pp);
    }
    sh.red[bg * H + c] = pp;
  }
  __syncthreads();
  if (bg == 0) {
    const float invp = 1.0f / fmaxf(sh.cnt, 1.0f);
    sh.pooled[c] = (sh.red[c] + sh.red[H + c] + sh.red[2*H + c] + sh.red[3*H + c]) * invp;
  }
  __syncthreads();

  // ---------------- Phase 6: latent1 = relu(pooled @ w_f1 + b_f1) --------
  {
    const int d  = tid & (D - 1);
    const int hh = tid >> 8;               // 0/1: split K=128 in halves
    const float* wf = w_f1 + d;
    float acc = 0.f;
    const int k0 = hh * 64;
    #pragma unroll 8
    for (int k = 0; k < 64; ++k)
      acc = fmaf(sh.pooled[k0 + k], wf[(k0 + k) * D], acc);
    sh.red[hh * D + d] = acc;
  }
  __syncthreads();
  if (tid < D) {
    sh.latent1[tid] = fmaxf(sh.red[tid] + sh.red[D + tid] + b_f1[tid], 0.f);
  }
  __syncthreads();

  // ---------------- Phase 7: out = latent1 @ w_f2 + b_f2 -----------------
  {
    const int d  = tid & (D - 1);
    const int hh = tid >> 8;               // split K=256 in halves
    const float* wf = w_f2 + d;
    float acc = 0.f;
    const int k0 = hh * 128;
    #pragma unroll 8
    for (int k = 0; k < 128; ++k)
      acc = fmaf(sh.latent1[k0 + k], wf[(k0 + k) * D], acc);
    sh.red[hh * D + d] = acc;
  }
  __syncthreads();
  if (tid < D) {
    out[(size_t)n * D + tid] = sh.red[tid] + sh.red[D + tid] + b_f2[tid];
  }
}

extern "C" void kernel_launch(void* const* d_in, const int* in_sizes, int n_in,
                              void* d_out, int out_size, void* d_ws, size_t ws_size,
                              hipStream_t stream) {
  const float* states = (const float*)d_in[0];
  const float* masks  = (const float*)d_in[1];
  const float* w_a  = (const float*)d_in[2];
  const float* b_a  = (const float*)d_in[3];
  const float* w_r1 = (const float*)d_in[4];
  const float* b_r1 = (const float*)d_in[5];
  const float* w_r2 = (const float*)d_in[6];
  const float* b_r2 = (const float*)d_in[7];
  const float* w_g  = (const float*)d_in[8];
  const float* b_g  = (const float*)d_in[9];
  const float* w_f1 = (const float*)d_in[10];
  const float* b_f1 = (const float*)d_in[11];
  const float* w_f2 = (const float*)d_in[12];
  const float* b_f2 = (const float*)d_in[13];
  float* out = (float*)d_out;
  hipLaunchKernelGGL(rpe_kernel, dim3(NBLK), dim3(BLOCK), 0, stream,
                     states, masks, w_a, b_a, w_r1, b_r1, w_r2, b_r2,
                     w_g, b_g, w_f1, b_f1, w_f2, b_f2, out);
}

// Round 2
// 82.425 us; speedup vs baseline: 1.1795x; 1.1795x over previous
//
#include <hip/hip_runtime.h>

#define KA 50
#define KP 52
#define FDIM 6
#define H 128
#define D 256
#define NBLK 256
#define BLOCK 1024
#define NG 8     // thread groups; also a-rows per geo chunk
#define RPT 7    // ceil(KP/NG) rows per thread

__device__ __forceinline__ float bf2f(unsigned short u) {
  return __uint_as_float(((unsigned)u) << 16);
}
__device__ __forceinline__ unsigned short f2bf(float f) {
  unsigned u = __float_as_uint(f);
  u = (u + 0x7FFFu + ((u >> 16) & 1u)) >> 16;   // RNE bf16
  return (unsigned short)u;
}

struct Smem {
  float s[KA][FDIM];
  float m[KA];
  float cnta[KA];
  float invden[KA];
  float cnt;
  unsigned short af[KP][H];     // agent_feat bf16
  unsigned short xi[KP][H];     // x_i bf16; becomes agg after phase 4
  unsigned short xj[KP][H];     // x_j bf16
  unsigned short hsum[KP][H];   // masked relu-sum over b, bf16
  union alignas(16) U {
    float geo[NG][KP][4];       // dist, angle, speed_diff, m[b]  (6656 B)
    float red[1024];            // reduction scratch (4096 B)
  } u;
  float pooled[H];
  float latent1[D];
};

__global__ void __launch_bounds__(BLOCK) rpe_kernel(
    const float* __restrict__ states, const float* __restrict__ masks,
    const float* __restrict__ w_a,  const float* __restrict__ b_a,
    const float* __restrict__ w_r1, const float* __restrict__ b_r1,
    const float* __restrict__ w_r2, const float* __restrict__ b_r2,
    const float* __restrict__ w_g,  const float* __restrict__ b_g,
    const float* __restrict__ w_f1, const float* __restrict__ b_f1,
    const float* __restrict__ w_f2, const float* __restrict__ b_f2,
    float* __restrict__ out) {
  __shared__ Smem sh;
  const int n = blockIdx.x;
  const int tid = threadIdx.x;
  const int c = tid & (H - 1);
  const int bg = tid >> 7;   // 0..7

  // ---------------- Phase 0: stage states, masks ------------------------
  {
    const float* sp = states + (size_t)n * (KA * FDIM);
    if (tid < KA * FDIM) (&sh.s[0][0])[tid] = sp[tid];
    if (tid < KA) sh.m[tid] = masks[(size_t)n * KA + tid];
  }
  __syncthreads();
  if (tid == 0) {
    float csum = 0.f;
    for (int b = 0; b < KA; ++b) csum += sh.m[b];
    sh.cnt = csum;
  }
  // ---------------- Phase 1: agent_feat = relu(s @ w_a + b_a) ------------
  {
    const float bac = b_a[c];
    const float w0 = w_a[0*H+c], w1 = w_a[1*H+c], w2 = w_a[2*H+c];
    const float w3 = w_a[3*H+c], w4 = w_a[4*H+c], w5 = w_a[5*H+c];
    #pragma unroll
    for (int r = 0; r < RPT; ++r) {
      const int a = bg + NG*r;
      if (a < KA) {
        const float* srow = sh.s[a];
        float v = fmaf(srow[0], w0, fmaf(srow[1], w1, fmaf(srow[2], w2,
                  fmaf(srow[3], w3, fmaf(srow[4], w4, fmaf(srow[5], w5, bac))))));
        sh.af[a][c] = f2bf(fmaxf(v, 0.f));
      }
    }
  }
  __syncthreads();
  if (tid < KA) {
    const float ca = sh.m[tid] * sh.cnt;       // sum_b mask_pairs for row a
    sh.cnta[tid] = ca;
    sh.invden[tid] = 1.0f / fmaxf(ca, 1.0f);
  }

  // ---------------- Phase 2: x_i, x_j -> LDS bf16 -------------------------
  {
    float acci[RPT], accj[RPT];
    #pragma unroll
    for (int r = 0; r < RPT; ++r) { acci[r] = 0.f; accj[r] = 0.f; }
    const float* wi = w_r1 + c;            // rows 0..127
    const float* wj = w_r1 + H * H + c;    // rows 128..255
    for (int k = 0; k < H; k += 4) {
      const float wi0 = wi[(k+0)*H], wi1 = wi[(k+1)*H], wi2 = wi[(k+2)*H], wi3 = wi[(k+3)*H];
      const float wj0 = wj[(k+0)*H], wj1 = wj[(k+1)*H], wj2 = wj[(k+2)*H], wj3 = wj[(k+3)*H];
      #pragma unroll
      for (int r = 0; r < RPT; ++r) {
        const int a = bg + NG*r;
        if (a < KA) {
          const ushort4 p = *reinterpret_cast<const ushort4*>(&sh.af[a][k]);
          const float f0 = bf2f(p.x), f1 = bf2f(p.y), f2v = bf2f(p.z), f3 = bf2f(p.w);
          acci[r] = fmaf(f0, wi0, acci[r]); acci[r] = fmaf(f1, wi1, acci[r]);
          acci[r] = fmaf(f2v, wi2, acci[r]); acci[r] = fmaf(f3, wi3, acci[r]);
          accj[r] = fmaf(f0, wj0, accj[r]); accj[r] = fmaf(f1, wj1, accj[r]);
          accj[r] = fmaf(f2v, wj2, accj[r]); accj[r] = fmaf(f3, wj3, accj[r]);
        }
      }
    }
    #pragma unroll
    for (int r = 0; r < RPT; ++r) {
      const int a = bg + NG*r;
      if (a < KA) {
        sh.xi[a][c] = f2bf(acci[r]);
        sh.xj[a][c] = f2bf(accj[r]);
      }
    }
  }
  __syncthreads();

  // ---------------- Phase 3: pair loop -> hsum (8 a-rows per chunk) -------
  {
    const float wgd  = w_r1[256*H + c];
    const float wgan = w_r1[257*H + c];
    const float wgs  = w_r1[258*H + c];
    const float br1c = b_r1[c];
    for (int a0 = 0; a0 < KA; a0 += NG) {
      // stage geo for rows a0..a0+7: one pair per thread, 512 threads active
      if (tid < NG * 64) {
        const int ao = tid >> 6;
        const int b  = tid & 63;
        const int a  = a0 + ao;
        if (b < KA && a < KA) {
          const float rx  = sh.s[b][0] - sh.s[a][0];
          const float ry  = sh.s[b][1] - sh.s[a][1];
          const float dvx = sh.s[b][2] - sh.s[a][2];
          const float dvy = sh.s[b][3] - sh.s[a][3];
          const float sq   = fmaf(rx, rx, ry*ry);
          const float dist = (sq == 0.f) ? 0.f : sqrtf(sq);
          const float sx   = (rx == 0.f && ry == 0.f) ? 1.f : rx;
          const float ang  = atan2f(ry, sx);
          const float sq2  = fmaf(dvx, dvx, dvy*dvy);
          const float sd   = (sq2 == 0.f) ? 0.f : sqrtf(sq2);
          float* gg = sh.u.geo[ao][b];
          gg[0] = dist; gg[1] = ang; gg[2] = sd; gg[3] = sh.m[b];
        }
      }
      __syncthreads();
      const int a = a0 + bg;
      if (a < KA) {
        float hacc = 0.f;
        if (sh.m[a] != 0.f) {               // wave-uniform
          const float xiv = bf2f(sh.xi[a][c]);
          #pragma unroll 5
          for (int b = 0; b < KA; ++b) {
            const float4 g = *reinterpret_cast<const float4*>(sh.u.geo[bg][b]);
            const float gv = fmaf(g.x, wgd, fmaf(g.y, wgan, fmaf(g.z, wgs, br1c)));
            const float xjv = bf2f(sh.xj[b][c]);
            hacc = fmaf(g.w, fmaxf(xiv + xjv + gv, 0.f), hacc);
          }
        }
        sh.hsum[a][c] = f2bf(hacc);
      }
      __syncthreads();
    }
  }

  // ---------------- Phase 4: agg = (hsum@w_r2 + cnta*b_r2)*invden -> xi --
  {
    float acc[RPT];
    #pragma unroll
    for (int r = 0; r < RPT; ++r) acc[r] = 0.f;
    const float* wr2 = w_r2 + c;
    for (int k = 0; k < H; k += 4) {
      const float w0 = wr2[(k+0)*H], w1 = wr2[(k+1)*H], w2 = wr2[(k+2)*H], w3 = wr2[(k+3)*H];
      #pragma unroll
      for (int r = 0; r < RPT; ++r) {
        const int a = bg + NG*r;
        if (a < KA) {
          const ushort4 hv = *reinterpret_cast<const ushort4*>(&sh.hsum[a][k]);
          acc[r] = fmaf(bf2f(hv.x), w0, acc[r]);
          acc[r] = fmaf(bf2f(hv.y), w1, acc[r]);
          acc[r] = fmaf(bf2f(hv.z), w2, acc[r]);
          acc[r] = fmaf(bf2f(hv.w), w3, acc[r]);
        }
      }
    }
    const float br2c = b_r2[c];
    __syncthreads();   // all hsum reads done before xi overwrite below
    #pragma unroll
    for (int r = 0; r < RPT; ++r) {
      const int a = bg + NG*r;
      if (a < KA) {
        const float v = fmaf(sh.cnta[a], br2c, acc[r]) * sh.invden[a];
        sh.xi[a][c] = f2bf(v);   // xi now holds agg (bf16)
      }
    }
  }
  __syncthreads();

  // ---------------- Phase 5: combined + masked pooling -------------------
  {
    float acc[RPT];
    #pragma unroll
    for (int r = 0; r < RPT; ++r) acc[r] = 0.f;
    const float* wga = w_g + c;            // rows 0..127 (agent_feat part)
    const float* wgb = w_g + H * H + c;    // rows 128..255 (agg part)
    for (int k = 0; k < H; k += 4) {
      const float a0w = wga[(k+0)*H], a1w = wga[(k+1)*H], a2w = wga[(k+2)*H], a3w = wga[(k+3)*H];
      const float b0w = wgb[(k+0)*H], b1w = wgb[(k+1)*H], b2w = wgb[(k+2)*H], b3w = wgb[(k+3)*H];
      #pragma unroll
      for (int r = 0; r < RPT; ++r) {
        const int a = bg + NG*r;
        if (a < KA) {
          const ushort4 pa = *reinterpret_cast<const ushort4*>(&sh.af[a][k]);
          const ushort4 pg = *reinterpret_cast<const ushort4*>(&sh.xi[a][k]);
          acc[r] = fmaf(bf2f(pa.x), a0w, acc[r]);
          acc[r] = fmaf(bf2f(pa.y), a1w, acc[r]);
          acc[r] = fmaf(bf2f(pa.z), a2w, acc[r]);
          acc[r] = fmaf(bf2f(pa.w), a3w, acc[r]);
          acc[r] = fmaf(bf2f(pg.x), b0w, acc[r]);
          acc[r] = fmaf(bf2f(pg.y), b1w, acc[r]);
          acc[r] = fmaf(bf2f(pg.z), b2w, acc[r]);
          acc[r] = fmaf(bf2f(pg.w), b3w, acc[r]);
        }
      }
    }
    const float bgc = b_g[c];
    float pp = 0.f;
    #pragma unroll
    for (int r = 0; r < RPT; ++r) {
      const int a = bg + NG*r;
      if (a < KA) pp = fmaf(sh.m[a], fmaxf(acc[r] + bgc, 0.f), pp);
    }
    sh.u.red[bg * H + c] = pp;   // geo dead; red live from here
  }
  __syncthreads();
  if (bg == 0) {
    const float invp = 1.0f / fmaxf(sh.cnt, 1.0f);
    float t = 0.f;
    #pragma unroll
    for (int g = 0; g < NG; ++g) t += sh.u.red[g * H + c];
    sh.pooled[c] = t * invp;
  }
  __syncthreads();

  // ---------------- Phase 6: latent1 = relu(pooled @ w_f1 + b_f1) --------
  {
    const int d  = tid & (D - 1);
    const int hh = tid >> 8;               // 0..3: split K=128 in quarters
    const float* wf = w_f1 + d;
    float acc = 0.f;
    const int k0 = hh * 32;
    #pragma unroll 8
    for (int k = 0; k < 32; ++k)
      acc = fmaf(sh.pooled[k0 + k], wf[(k0 + k) * D], acc);
    sh.u.red[hh * D + d] = acc;
  }
  __syncthreads();
  if (tid < D) {
    sh.latent1[tid] = fmaxf(sh.u.red[tid] + sh.u.red[D + tid] +
                            sh.u.red[2*D + tid] + sh.u.red[3*D + tid] +
                            b_f1[tid], 0.f);
  }
  __syncthreads();

  // ---------------- Phase 7: out = latent1 @ w_f2 + b_f2 -----------------
  {
    const int d  = tid & (D - 1);
    const int hh = tid >> 8;               // split K=256 in quarters
    const float* wf = w_f2 + d;
    float acc = 0.f;
    const int k0 = hh * 64;
    #pragma unroll 8
    for (int k = 0; k < 64; ++k)
      acc = fmaf(sh.latent1[k0 + k], wf[(k0 + k) * D], acc);
    __syncthreads();   // latent1 reads done; red reuse safe
    sh.u.red[hh * D + d] = acc;
  }
  __syncthreads();
  if (tid < D) {
    out[(size_t)n * D + tid] = sh.u.red[tid] + sh.u.red[D + tid] +
                               sh.u.red[2*D + tid] + sh.u.red[3*D + tid] +
                               b_f2[tid];
  }
}

extern "C" void kernel_launch(void* const* d_in, const int* in_sizes, int n_in,
                              void* d_out, int out_size, void* d_ws, size_t ws_size,
                              hipStream_t stream) {
  const float* states = (const float*)d_in[0];
  const float* masks  = (const float*)d_in[1];
  const float* w_a  = (const float*)d_in[2];
  const float* b_a  = (const float*)d_in[3];
  const float* w_r1 = (const float*)d_in[4];
  const float* b_r1 = (const float*)d_in[5];
  const float* w_r2 = (const float*)d_in[6];
  const float* b_r2 = (const float*)d_in[7];
  const float* w_g  = (const float*)d_in[8];
  const float* b_g  = (const float*)d_in[9];
  const float* w_f1 = (const float*)d_in[10];
  const float* b_f1 = (const float*)d_in[11];
  const float* w_f2 = (const float*)d_in[12];
  const float* b_f2 = (const float*)d_in[13];
  float* out = (float*)d_out;
  hipLaunchKernelGGL(rpe_kernel, dim3(NBLK), dim3(BLOCK), 0, stream,
                     states, masks, w_a, b_a, w_r1, b_r1, w_r2, b_r2,
                     w_g, b_g, w_f1, b_f1, w_f2, b_f2, out);
}

// Round 3
// 53.438 us; speedup vs baseline: 1.8194x; 1.5424x over previous
//
#include <hip/hip_runtime.h>

#define KA 50
#define KP 52
#define H 128
#define D 256
#define NBLK 256
#define BLOCK 1024
#define NG 8
#define RPT 7
#define STRD 136   // shorts; row stride for af/xi/hsum (272B, 16B-aligned, 2-way bank alias only)

// B-fragment pack bases (units of 512-short fragments)
#define WS_WI 0
#define WS_WJ 32
#define WS_WR2 64
#define WS_WG 96
#define NFRAG 160

typedef __attribute__((ext_vector_type(8))) short bf16x8;
typedef __attribute__((ext_vector_type(4))) float f32x4;

__device__ __forceinline__ float bf2f(unsigned short u) {
  return __uint_as_float(((unsigned)u) << 16);
}
__device__ __forceinline__ unsigned short f2bf(float f) {
  unsigned u = __float_as_uint(f);
  u = (u + 0x7FFFu + ((u >> 16) & 1u)) >> 16;   // RNE bf16
  return (unsigned short)u;
}

// ---- pre-pass: pack weights into bf16 MFMA B-fragment order in d_ws ------
// fragment f=(kt*8+ct): lane l holds B[kt*32+(l>>4)*8+j][ct*16+(l&15)], j=0..7
__global__ void pack_weights(const float* __restrict__ w_r1,
                             const float* __restrict__ w_r2,
                             const float* __restrict__ w_g,
                             unsigned short* __restrict__ wp) {
  const int t = blockIdx.x * 256 + threadIdx.x;
  if (t >= NFRAG * 64) return;
  const int f = t >> 6, lane = t & 63;
  const float* W; int rowbase, sf;
  if (f < 64)       { W = w_r1; rowbase = (f < 32) ? 0 : 128; sf = f & 31; }
  else if (f < 96)  { W = w_r2; rowbase = 0; sf = f - 64; }
  else              { W = w_g;  rowbase = 0; sf = f - 96; }
  const int kt = sf >> 3, ctl = sf & 7;
  const int col = ctl * 16 + (lane & 15);
  const int k0  = rowbase + kt * 32 + (lane >> 4) * 8;
  unsigned short v[8];
  #pragma unroll
  for (int j = 0; j < 8; ++j) v[j] = f2bf(W[(k0 + j) * H + col]);
  #pragma unroll
  for (int j = 0; j < 8; ++j) wp[(size_t)t * 8 + j] = v[j];
}

struct Smem {
  unsigned short af[KP * STRD];    // agent_feat bf16 (rows 50,51 zeroed)
  unsigned short xi[KP * STRD];    // x_i bf16; becomes agg after phase 4
  unsigned short xj[KP * H];       // x_j bf16 (elementwise reads only)
  unsigned short hsum[KP * STRD];  // masked relu-sum over b, bf16
  union U {
    float geo[NG][KP][4];          // dist, angle, speed_diff, m[b]
    struct R { float red[1024]; float pooled[H]; float latent1[D]; } r;
  } u;
  float s[KA][6];
  float m[64];                     // padded with zeros
  float cnta[KP];
  float invden[KP];
  float cnt;
};

__global__ void __launch_bounds__(BLOCK) rpe_kernel(
    const float* __restrict__ states, const float* __restrict__ masks,
    const float* __restrict__ w_a,  const float* __restrict__ b_a,
    const float* __restrict__ w_r1, const float* __restrict__ b_r1,
    const float* __restrict__ b_r2,
    const float* __restrict__ b_g,
    const float* __restrict__ w_f1, const float* __restrict__ b_f1,
    const float* __restrict__ w_f2, const float* __restrict__ b_f2,
    const unsigned short* __restrict__ wp,
    float* __restrict__ out) {
  __shared__ Smem sh;
  const int n = blockIdx.x;
  const int tid = threadIdx.x;
  const int c = tid & (H - 1);
  const int bg = tid >> 7;            // 0..7
  const int w = tid >> 6, lane = tid & 63;
  const int ct = w & 7;               // col tile 0..7
  const int rtb = (w >> 3) * 2;       // row tiles rtb, rtb+1
  const int fr = lane & 15;           // A-row / B-col / C-col within tile
  const int fkg = lane >> 4;          // k-group (A/B), C row-group

  // ---------------- Phase 0: stage states, masks, zero pads ---------------
  {
    if (tid < KA * 6) ((float*)sh.s)[tid] = states[(size_t)n * (KA * 6) + tid];
    if (tid < 64) sh.m[tid] = (tid < KA) ? masks[(size_t)n * KA + tid] : 0.f;
    if (tid < 2 * H) {
      const int r5 = KA + (tid >> 7), cc = tid & (H - 1);
      sh.af[r5 * STRD + cc] = 0;
      sh.hsum[r5 * STRD + cc] = 0;
    }
  }
  __syncthreads();
  if (tid == 0) {
    float cs = 0.f;
    for (int b = 0; b < KA; ++b) cs += sh.m[b];
    sh.cnt = cs;
  }
  // ---------------- Phase 1: agent_feat = relu(s @ w_a + b_a) -------------
  {
    const float bac = b_a[c];
    const float w0 = w_a[0*H+c], w1 = w_a[1*H+c], w2 = w_a[2*H+c];
    const float w3 = w_a[3*H+c], w4 = w_a[4*H+c], w5 = w_a[5*H+c];
    #pragma unroll
    for (int r = 0; r < RPT; ++r) {
      const int a = bg + NG * r;
      if (a < KA) {
        const float* srow = sh.s[a];
        float v = fmaf(srow[0], w0, fmaf(srow[1], w1, fmaf(srow[2], w2,
                  fmaf(srow[3], w3, fmaf(srow[4], w4, fmaf(srow[5], w5, bac))))));
        sh.af[a * STRD + c] = f2bf(fmaxf(v, 0.f));
      }
    }
  }
  __syncthreads();
  if (tid < KP) {
    const float ca = (tid < KA) ? sh.m[tid] * sh.cnt : 0.f;
    sh.cnta[tid] = ca;
    sh.invden[tid] = 1.0f / fmaxf(ca, 1.0f);
  }

  // ---------------- Phase 2 (MFMA): xi = af@wi, xj = af@wj ----------------
  {
    f32x4 ci0 = {0,0,0,0}, ci1 = {0,0,0,0}, cj0 = {0,0,0,0}, cj1 = {0,0,0,0};
    #pragma unroll
    for (int kt = 0; kt < 4; ++kt) {
      const bf16x8 Bi = *(const bf16x8*)&wp[(size_t)((WS_WI + kt*8 + ct) * 64 + lane) * 8];
      const bf16x8 Bj = *(const bf16x8*)&wp[(size_t)((WS_WJ + kt*8 + ct) * 64 + lane) * 8];
      const bf16x8 A0 = *(const bf16x8*)&sh.af[(rtb*16 + fr) * STRD + kt*32 + fkg*8];
      const bf16x8 A1 = *(const bf16x8*)&sh.af[((rtb+1)*16 + fr) * STRD + kt*32 + fkg*8];
      ci0 = __builtin_amdgcn_mfma_f32_16x16x32_bf16(A0, Bi, ci0, 0, 0, 0);
      ci1 = __builtin_amdgcn_mfma_f32_16x16x32_bf16(A1, Bi, ci1, 0, 0, 0);
      cj0 = __builtin_amdgcn_mfma_f32_16x16x32_bf16(A0, Bj, cj0, 0, 0, 0);
      cj1 = __builtin_amdgcn_mfma_f32_16x16x32_bf16(A1, Bj, cj1, 0, 0, 0);
    }
    const int col = ct * 16 + fr;
    #pragma unroll
    for (int rt2 = 0; rt2 < 2; ++rt2) {
      const f32x4 vi = rt2 ? ci1 : ci0;
      const f32x4 vj = rt2 ? cj1 : cj0;
      #pragma unroll
      for (int g = 0; g < 4; ++g) {
        const int r = (rtb + rt2) * 16 + fkg * 4 + g;
        if (r < KP) {   // rows 50,51 are exact zeros (af pad rows zeroed)
          sh.xi[r * STRD + col] = f2bf(vi[g]);
          sh.xj[r * H + col]    = f2bf(vj[g]);
        }
      }
    }
  }
  __syncthreads();

  // ---------------- Phase 3 (VALU): pair loop -> hsum ---------------------
  {
    const float wgd  = w_r1[256*H + c];
    const float wgan = w_r1[257*H + c];
    const float wgs  = w_r1[258*H + c];
    const float br1c = b_r1[c];
    for (int a0 = 0; a0 < KA; a0 += NG) {
      if (tid < NG * 64) {
        const int ao = tid >> 6;
        const int b  = tid & 63;
        const int a  = a0 + ao;
        if (b < KA && a < KA) {
          const float rx  = sh.s[b][0] - sh.s[a][0];
          const float ry  = sh.s[b][1] - sh.s[a][1];
          const float dvx = sh.s[b][2] - sh.s[a][2];
          const float dvy = sh.s[b][3] - sh.s[a][3];
          const float sq   = fmaf(rx, rx, ry*ry);
          const float dist = (sq == 0.f) ? 0.f : sqrtf(sq);
          const float sx   = (rx == 0.f && ry == 0.f) ? 1.f : rx;
          const float ang  = atan2f(ry, sx);
          const float sq2  = fmaf(dvx, dvx, dvy*dvy);
          const float sd   = (sq2 == 0.f) ? 0.f : sqrtf(sq2);
          float* gg = sh.u.geo[ao][b];
          gg[0] = dist; gg[1] = ang; gg[2] = sd; gg[3] = sh.m[b];
        }
      }
      __syncthreads();
      const int a = a0 + bg;
      if (a < KA) {
        float hacc = 0.f;
        if (sh.m[a] != 0.f) {               // wave-uniform
          const float xiv = bf2f(sh.xi[a * STRD + c]);
          #pragma unroll 5
          for (int b = 0; b < KA; ++b) {
            const float4 g = *reinterpret_cast<const float4*>(sh.u.geo[bg][b]);
            const float gv = fmaf(g.x, wgd, fmaf(g.y, wgan, fmaf(g.z, wgs, br1c)));
            hacc = fmaf(g.w, fmaxf(xiv + bf2f(sh.xj[b * H + c]) + gv, 0.f), hacc);
          }
        }
        sh.hsum[a * STRD + c] = f2bf(hacc);
      }
      __syncthreads();
    }
  }

  // ---------------- Phase 4 (MFMA): agg = (hsum@wr2 + cnta*b_r2)*invden ---
  {
    f32x4 a0 = {0,0,0,0}, a1 = {0,0,0,0};
    #pragma unroll
    for (int kt = 0; kt < 4; ++kt) {
      const bf16x8 B = *(const bf16x8*)&wp[(size_t)((WS_WR2 + kt*8 + ct) * 64 + lane) * 8];
      const bf16x8 A0 = *(const bf16x8*)&sh.hsum[(rtb*16 + fr) * STRD + kt*32 + fkg*8];
      const bf16x8 A1 = *(const bf16x8*)&sh.hsum[((rtb+1)*16 + fr) * STRD + kt*32 + fkg*8];
      a0 = __builtin_amdgcn_mfma_f32_16x16x32_bf16(A0, B, a0, 0, 0, 0);
      a1 = __builtin_amdgcn_mfma_f32_16x16x32_bf16(A1, B, a1, 0, 0, 0);
    }
    const int col = ct * 16 + fr;
    const float br2c = b_r2[col];
    #pragma unroll
    for (int rt2 = 0; rt2 < 2; ++rt2) {
      const f32x4 v = rt2 ? a1 : a0;
      #pragma unroll
      for (int g = 0; g < 4; ++g) {
        const int r = (rtb + rt2) * 16 + fkg * 4 + g;
        if (r < KP) {
          const float val = fmaf(sh.cnta[r], br2c, v[g]) * sh.invden[r];
          sh.xi[r * STRD + col] = f2bf(val);   // xi now holds agg
        }
      }
    }
  }
  __syncthreads();

  // ---------------- Phase 5 (MFMA): combined + masked pooling -------------
  {
    f32x4 a0 = {0,0,0,0}, a1 = {0,0,0,0};
    #pragma unroll
    for (int kt = 0; kt < 4; ++kt) {   // af part (w_g rows 0..127)
      const bf16x8 B = *(const bf16x8*)&wp[(size_t)((WS_WG + kt*8 + ct) * 64 + lane) * 8];
      const bf16x8 A0 = *(const bf16x8*)&sh.af[(rtb*16 + fr) * STRD + kt*32 + fkg*8];
      const bf16x8 A1 = *(const bf16x8*)&sh.af[((rtb+1)*16 + fr) * STRD + kt*32 + fkg*8];
      a0 = __builtin_amdgcn_mfma_f32_16x16x32_bf16(A0, B, a0, 0, 0, 0);
      a1 = __builtin_amdgcn_mfma_f32_16x16x32_bf16(A1, B, a1, 0, 0, 0);
    }
    #pragma unroll
    for (int kt = 0; kt < 4; ++kt) {   // agg part (w_g rows 128..255)
      const bf16x8 B = *(const bf16x8*)&wp[(size_t)((WS_WG + (kt+4)*8 + ct) * 64 + lane) * 8];
      const bf16x8 A0 = *(const bf16x8*)&sh.xi[(rtb*16 + fr) * STRD + kt*32 + fkg*8];
      const bf16x8 A1 = *(const bf16x8*)&sh.xi[((rtb+1)*16 + fr) * STRD + kt*32 + fkg*8];
      a0 = __builtin_amdgcn_mfma_f32_16x16x32_bf16(A0, B, a0, 0, 0, 0);
      a1 = __builtin_amdgcn_mfma_f32_16x16x32_bf16(A1, B, a1, 0, 0, 0);
    }
    const int col = ct * 16 + fr;
    const float bgc = b_g[col];
    float pv = 0.f;
    #pragma unroll
    for (int rt2 = 0; rt2 < 2; ++rt2) {
      const f32x4 v = rt2 ? a1 : a0;
      #pragma unroll
      for (int g = 0; g < 4; ++g) {
        const int r = (rtb + rt2) * 16 + fkg * 4 + g;
        if (r < KA) {   // skip pad + OOB-garbage rows entirely (NaN-safe)
          pv = fmaf(sh.m[r], fmaxf(v[g] + bgc, 0.f), pv);
        }
      }
    }
    pv += __shfl_xor(pv, 16);
    pv += __shfl_xor(pv, 32);
    if (lane < 16) sh.u.r.red[(w >> 3) * H + col] = pv;
  }
  __syncthreads();
  if (tid < H) {
    const float invp = 1.0f / fmaxf(sh.cnt, 1.0f);
    sh.u.r.pooled[tid] = (sh.u.r.red[tid] + sh.u.r.red[H + tid]) * invp;
  }
  __syncthreads();

  // ---------------- Phase 6: latent1 = relu(pooled @ w_f1 + b_f1) ---------
  {
    const int d  = tid & (D - 1);
    const int hh = tid >> 8;               // 0..3: K=128 in quarters
    const float* wf = w_f1 + d;
    float acc = 0.f;
    const int k0 = hh * 32;
    #pragma unroll 8
    for (int k = 0; k < 32; ++k)
      acc = fmaf(sh.u.r.pooled[k0 + k], wf[(k0 + k) * D], acc);
    sh.u.r.red[hh * D + d] = acc;
  }
  __syncthreads();
  if (tid < D) {
    sh.u.r.latent1[tid] = fmaxf(sh.u.r.red[tid] + sh.u.r.red[D + tid] +
                                sh.u.r.red[2*D + tid] + sh.u.r.red[3*D + tid] +
                                b_f1[tid], 0.f);
  }
  __syncthreads();

  // ---------------- Phase 7: out = latent1 @ w_f2 + b_f2 ------------------
  {
    const int d  = tid & (D - 1);
    const int hh = tid >> 8;               // K=256 in quarters
    const float* wf = w_f2 + d;
    float acc = 0.f;
    const int k0 = hh * 64;
    #pragma unroll 8
    for (int k = 0; k < 64; ++k)
      acc = fmaf(sh.u.r.latent1[k0 + k], wf[(k0 + k) * D], acc);
    __syncthreads();
    sh.u.r.red[hh * D + d] = acc;
  }
  __syncthreads();
  if (tid < D) {
    out[(size_t)n * D + tid] = sh.u.r.red[tid] + sh.u.r.red[D + tid] +
                               sh.u.r.red[2*D + tid] + sh.u.r.red[3*D + tid] +
                               b_f2[tid];
  }
}

extern "C" void kernel_launch(void* const* d_in, const int* in_sizes, int n_in,
                              void* d_out, int out_size, void* d_ws, size_t ws_size,
                              hipStream_t stream) {
  const float* states = (const float*)d_in[0];
  const float* masks  = (const float*)d_in[1];
  const float* w_a  = (const float*)d_in[2];
  const float* b_a  = (const float*)d_in[3];
  const float* w_r1 = (const float*)d_in[4];
  const float* b_r1 = (const float*)d_in[5];
  const float* w_r2 = (const float*)d_in[6];
  const float* b_r2 = (const float*)d_in[7];
  const float* w_g  = (const float*)d_in[8];
  const float* b_g  = (const float*)d_in[9];
  const float* w_f1 = (const float*)d_in[10];
  const float* b_f1 = (const float*)d_in[11];
  const float* w_f2 = (const float*)d_in[12];
  const float* b_f2 = (const float*)d_in[13];
  float* out = (float*)d_out;
  unsigned short* wp = (unsigned short*)d_ws;

  hipLaunchKernelGGL(pack_weights, dim3((NFRAG * 64 + 255) / 256), dim3(256), 0, stream,
                     w_r1, w_r2, w_g, wp);
  hipLaunchKernelGGL(rpe_kernel, dim3(NBLK), dim3(BLOCK), 0, stream,
                     states, masks, w_a, b_a, w_r1, b_r1, b_r2,
                     b_g, w_f1, b_f1, w_f2, b_f2, wp, out);
}

// Round 4
// 41.137 us; speedup vs baseline: 2.3634x; 1.2990x over previous
//
#include <hip/hip_runtime.h>

#define KA 50
#define KP 52
#define H 128
#define D 256
#define NBLK 256
#define BLOCK 1024
#define NG 8
#define RPT 7
#define CHUNK 16   // a-rows per geo chunk (== number of waves)
#define STRD 136   // shorts; row stride for af/xi/hsum

// B-fragment pack bases (units of 512-short fragments)
#define WS_WI 0
#define WS_WJ 32
#define WS_WR2 64
#define WS_WG 96
#define NFRAG 160

typedef __attribute__((ext_vector_type(8))) short bf16x8;
typedef __attribute__((ext_vector_type(4))) float f32x4;

__device__ __forceinline__ float bf2f(unsigned short u) {
  return __uint_as_float(((unsigned)u) << 16);
}
__device__ __forceinline__ unsigned short f2bf(float f) {
  unsigned u = __float_as_uint(f);
  u = (u + 0x7FFFu + ((u >> 16) & 1u)) >> 16;   // RNE bf16
  return (unsigned short)u;
}

// ---- pre-pass: pack weights into bf16 MFMA B-fragment order in d_ws ------
__global__ void pack_weights(const float* __restrict__ w_r1,
                             const float* __restrict__ w_r2,
                             const float* __restrict__ w_g,
                             unsigned short* __restrict__ wp) {
  const int t = blockIdx.x * 256 + threadIdx.x;
  if (t >= NFRAG * 64) return;
  const int f = t >> 6, lane = t & 63;
  const float* W; int rowbase, sf;
  if (f < 64)       { W = w_r1; rowbase = (f < 32) ? 0 : 128; sf = f & 31; }
  else if (f < 96)  { W = w_r2; rowbase = 0; sf = f - 64; }
  else              { W = w_g;  rowbase = 0; sf = f - 96; }
  const int kt = sf >> 3, ctl = sf & 7;
  const int col = ctl * 16 + (lane & 15);
  const int k0  = rowbase + kt * 32 + (lane >> 4) * 8;
  unsigned short v[8];
  #pragma unroll
  for (int j = 0; j < 8; ++j) v[j] = f2bf(W[(k0 + j) * H + col]);
  #pragma unroll
  for (int j = 0; j < 8; ++j) wp[(size_t)t * 8 + j] = v[j];
}

struct Smem {
  unsigned short af[KP * STRD];    // agent_feat bf16 (rows 50,51 zeroed)
  unsigned short xi[KP * STRD];    // x_i bf16; becomes agg after phase 4
  unsigned short xj[KP * H];       // x_j bf16, row-major [52][128]
  unsigned short hsum[KP * STRD];  // masked relu-sum over b, bf16
  union alignas(16) U {
    unsigned int geo[CHUNK][KA][2];  // (dist|ang)<<, (sd|m) bf16-packed; 6400 B
    struct R { float red[1024]; float pooled[H]; float latent1[D]; } r;
  } u;
  float s[KA][6];
  float m[64];                     // padded with zeros
  float cnta[KP];
  float invden[KP];
  float cnt;
};

__global__ void __launch_bounds__(BLOCK) rpe_kernel(
    const float* __restrict__ states, const float* __restrict__ masks,
    const float* __restrict__ w_a,  const float* __restrict__ b_a,
    const float* __restrict__ w_r1, const float* __restrict__ b_r1,
    const float* __restrict__ b_r2,
    const float* __restrict__ b_g,
    const float* __restrict__ w_f1, const float* __restrict__ b_f1,
    const float* __restrict__ w_f2, const float* __restrict__ b_f2,
    const unsigned short* __restrict__ wp,
    float* __restrict__ out) {
  __shared__ Smem sh;
  const int n = blockIdx.x;
  const int tid = threadIdx.x;
  const int c = tid & (H - 1);
  const int bg = tid >> 7;            // 0..7
  const int wid = tid >> 6, lane = tid & 63;
  const int ct = wid & 7;             // col tile 0..7 (MFMA phases)
  const int rtb = (wid >> 3) * 2;     // row tiles rtb, rtb+1
  const int fr = lane & 15;
  const int fkg = lane >> 4;

  // ---------------- Phase 0: stage states, masks, zero pads ---------------
  {
    if (tid < KA * 6) ((float*)sh.s)[tid] = states[(size_t)n * (KA * 6) + tid];
    if (tid < 64) sh.m[tid] = (tid < KA) ? masks[(size_t)n * KA + tid] : 0.f;
    if (tid < 2 * H) {
      const int r5 = KA + (tid >> 7), cc = tid & (H - 1);
      sh.af[r5 * STRD + cc] = 0;
      sh.hsum[r5 * STRD + cc] = 0;
    }
  }
  __syncthreads();
  if (tid == 0) {
    float cs = 0.f;
    for (int b = 0; b < KA; ++b) cs += sh.m[b];
    sh.cnt = cs;
  }
  // ---------------- Phase 1: agent_feat = relu(s @ w_a + b_a) -------------
  {
    const float bac = b_a[c];
    const float w0 = w_a[0*H+c], w1 = w_a[1*H+c], w2 = w_a[2*H+c];
    const float w3 = w_a[3*H+c], w4 = w_a[4*H+c], w5 = w_a[5*H+c];
    #pragma unroll
    for (int r = 0; r < RPT; ++r) {
      const int a = bg + NG * r;
      if (a < KA) {
        const float* srow = sh.s[a];
        float v = fmaf(srow[0], w0, fmaf(srow[1], w1, fmaf(srow[2], w2,
                  fmaf(srow[3], w3, fmaf(srow[4], w4, fmaf(srow[5], w5, bac))))));
        sh.af[a * STRD + c] = f2bf(fmaxf(v, 0.f));
      }
    }
  }
  __syncthreads();
  if (tid < KP) {
    const float ca = (tid < KA) ? sh.m[tid] * sh.cnt : 0.f;
    sh.cnta[tid] = ca;
    sh.invden[tid] = 1.0f / fmaxf(ca, 1.0f);
  }

  // ---------------- Phase 2 (MFMA): xi = af@wi, xj = af@wj ----------------
  {
    f32x4 ci0 = {0,0,0,0}, ci1 = {0,0,0,0}, cj0 = {0,0,0,0}, cj1 = {0,0,0,0};
    #pragma unroll
    for (int kt = 0; kt < 4; ++kt) {
      const bf16x8 Bi = *(const bf16x8*)&wp[(size_t)((WS_WI + kt*8 + ct) * 64 + lane) * 8];
      const bf16x8 Bj = *(const bf16x8*)&wp[(size_t)((WS_WJ + kt*8 + ct) * 64 + lane) * 8];
      const bf16x8 A0 = *(const bf16x8*)&sh.af[(rtb*16 + fr) * STRD + kt*32 + fkg*8];
      const bf16x8 A1 = *(const bf16x8*)&sh.af[((rtb+1)*16 + fr) * STRD + kt*32 + fkg*8];
      ci0 = __builtin_amdgcn_mfma_f32_16x16x32_bf16(A0, Bi, ci0, 0, 0, 0);
      ci1 = __builtin_amdgcn_mfma_f32_16x16x32_bf16(A1, Bi, ci1, 0, 0, 0);
      cj0 = __builtin_amdgcn_mfma_f32_16x16x32_bf16(A0, Bj, cj0, 0, 0, 0);
      cj1 = __builtin_amdgcn_mfma_f32_16x16x32_bf16(A1, Bj, cj1, 0, 0, 0);
    }
    const int col = ct * 16 + fr;
    #pragma unroll
    for (int rt2 = 0; rt2 < 2; ++rt2) {
      const f32x4 vi = rt2 ? ci1 : ci0;
      const f32x4 vj = rt2 ? cj1 : cj0;
      #pragma unroll
      for (int g = 0; g < 4; ++g) {
        const int r = (rtb + rt2) * 16 + fkg * 4 + g;
        if (r < KP) {
          sh.xi[r * STRD + col] = f2bf(vi[g]);
          sh.xj[r * H + col]    = f2bf(vj[g]);
        }
      }
    }
  }
  __syncthreads();

  // ---------------- Phase 3: pair loop -> hsum (LDS-free inner loop) ------
  {
    const int c0 = 2 * lane, c1 = 2 * lane + 1;
    const float wgd0  = w_r1[256*H + c0], wgd1  = w_r1[256*H + c1];
    const float wgan0 = w_r1[257*H + c0], wgan1 = w_r1[257*H + c1];
    const float wgs0  = w_r1[258*H + c0], wgs1  = w_r1[258*H + c1];
    const float br10  = b_r1[c0],         br11  = b_r1[c1];

    for (int a0 = 0; a0 < KA; a0 += CHUNK) {
      // stage geo bf16-packed: 1024 threads = 16 rows x 64 b-slots
      {
        const int ao = tid >> 6, b = tid & 63;
        const int a  = a0 + ao;
        if (a < KA && b < KA) {
          const float rx  = sh.s[b][0] - sh.s[a][0];
          const float ry  = sh.s[b][1] - sh.s[a][1];
          const float dvx = sh.s[b][2] - sh.s[a][2];
          const float dvy = sh.s[b][3] - sh.s[a][3];
          const float sq   = fmaf(rx, rx, ry*ry);
          const float dist = (sq == 0.f) ? 0.f : sqrtf(sq);
          const float sx   = (rx == 0.f && ry == 0.f) ? 1.f : rx;
          const float ang  = atan2f(ry, sx);
          const float sq2  = fmaf(dvx, dvx, dvy*dvy);
          const float sd   = (sq2 == 0.f) ? 0.f : sqrtf(sq2);
          const unsigned d0 = (unsigned)f2bf(dist) | ((unsigned)f2bf(ang) << 16);
          const unsigned d1 = (unsigned)f2bf(sd) |
                              ((sh.m[b] != 0.f) ? 0x3F800000u : 0u);  // m bf16 in hi
          *(uint2*)&sh.u.geo[ao][b][0] = make_uint2(d0, d1);
        }
      }
      __syncthreads();
      const int a = a0 + wid;           // one wave per a-row
      if (a < KA) {
        float h0 = 0.f, h1 = 0.f;
        if (sh.m[a] != 0.f) {           // wave-uniform
          uint2 g = make_uint2(0u, 0u);
          if (lane < KA) g = *(const uint2*)&sh.u.geo[wid][lane][0];
          const unsigned xip = *(const unsigned*)&sh.xi[a * STRD + c0];
          const float base0 = bf2f((unsigned short)xip) + br10;
          const float base1 = bf2f((unsigned short)(xip >> 16)) + br11;
          #pragma unroll
          for (int b = 0; b < KA; ++b) {
            const unsigned q1 = (unsigned)__builtin_amdgcn_readlane((int)g.y, b);
            const unsigned q0 = (unsigned)__builtin_amdgcn_readlane((int)g.x, b);
            const unsigned xjp = *(const unsigned*)&sh.xj[b * H + c0];
            if (q1 & 0xFFFF0000u) {     // m[b] != 0 (uniform scalar branch)
              const float dist = __uint_as_float(q0 << 16);
              const float ang  = __uint_as_float(q0 & 0xFFFF0000u);
              const float sd   = __uint_as_float(q1 << 16);
              float t0 = fmaf(dist, wgd0, base0);
              float t1 = fmaf(dist, wgd1, base1);
              t0 = fmaf(ang, wgan0, t0);  t1 = fmaf(ang, wgan1, t1);
              t0 = fmaf(sd,  wgs0,  t0);  t1 = fmaf(sd,  wgs1,  t1);
              t0 += __uint_as_float(xjp << 16);
              t1 += __uint_as_float(xjp & 0xFFFF0000u);
              h0 += fmaxf(t0, 0.f);       // m[b] == 1.0 exactly
              h1 += fmaxf(t1, 0.f);
            }
          }
        }
        *(unsigned*)&sh.hsum[a * STRD + c0] =
            (unsigned)f2bf(h0) | ((unsigned)f2bf(h1) << 16);
      }
      __syncthreads();
    }
  }

  // ---------------- Phase 4 (MFMA): agg = (hsum@wr2 + cnta*b_r2)*invden ---
  {
    f32x4 a0 = {0,0,0,0}, a1 = {0,0,0,0};
    #pragma unroll
    for (int kt = 0; kt < 4; ++kt) {
      const bf16x8 B = *(const bf16x8*)&wp[(size_t)((WS_WR2 + kt*8 + ct) * 64 + lane) * 8];
      const bf16x8 A0 = *(const bf16x8*)&sh.hsum[(rtb*16 + fr) * STRD + kt*32 + fkg*8];
      const bf16x8 A1 = *(const bf16x8*)&sh.hsum[((rtb+1)*16 + fr) * STRD + kt*32 + fkg*8];
      a0 = __builtin_amdgcn_mfma_f32_16x16x32_bf16(A0, B, a0, 0, 0, 0);
      a1 = __builtin_amdgcn_mfma_f32_16x16x32_bf16(A1, B, a1, 0, 0, 0);
    }
    const int col = ct * 16 + fr;
    const float br2c = b_r2[col];
    #pragma unroll
    for (int rt2 = 0; rt2 < 2; ++rt2) {
      const f32x4 v = rt2 ? a1 : a0;
      #pragma unroll
      for (int g = 0; g < 4; ++g) {
        const int r = (rtb + rt2) * 16 + fkg * 4 + g;
        if (r < KP) {
          const float val = fmaf(sh.cnta[r], br2c, v[g]) * sh.invden[r];
          sh.xi[r * STRD + col] = f2bf(val);   // xi now holds agg
        }
      }
    }
  }
  __syncthreads();

  // ---------------- Phase 5 (MFMA): combined + masked pooling -------------
  {
    f32x4 a0 = {0,0,0,0}, a1 = {0,0,0,0};
    #pragma unroll
    for (int kt = 0; kt < 4; ++kt) {   // af part (w_g rows 0..127)
      const bf16x8 B = *(const bf16x8*)&wp[(size_t)((WS_WG + kt*8 + ct) * 64 + lane) * 8];
      const bf16x8 A0 = *(const bf16x8*)&sh.af[(rtb*16 + fr) * STRD + kt*32 + fkg*8];
      const bf16x8 A1 = *(const bf16x8*)&sh.af[((rtb+1)*16 + fr) * STRD + kt*32 + fkg*8];
      a0 = __builtin_amdgcn_mfma_f32_16x16x32_bf16(A0, B, a0, 0, 0, 0);
      a1 = __builtin_amdgcn_mfma_f32_16x16x32_bf16(A1, B, a1, 0, 0, 0);
    }
    #pragma unroll
    for (int kt = 0; kt < 4; ++kt) {   // agg part (w_g rows 128..255)
      const bf16x8 B = *(const bf16x8*)&wp[(size_t)((WS_WG + (kt+4)*8 + ct) * 64 + lane) * 8];
      const bf16x8 A0 = *(const bf16x8*)&sh.xi[(rtb*16 + fr) * STRD + kt*32 + fkg*8];
      const bf16x8 A1 = *(const bf16x8*)&sh.xi[((rtb+1)*16 + fr) * STRD + kt*32 + fkg*8];
      a0 = __builtin_amdgcn_mfma_f32_16x16x32_bf16(A0, B, a0, 0, 0, 0);
      a1 = __builtin_amdgcn_mfma_f32_16x16x32_bf16(A1, B, a1, 0, 0, 0);
    }
    const int col = ct * 16 + fr;
    const float bgc = b_g[col];
    float pv = 0.f;
    #pragma unroll
    for (int rt2 = 0; rt2 < 2; ++rt2) {
      const f32x4 v = rt2 ? a1 : a0;
      #pragma unroll
      for (int g = 0; g < 4; ++g) {
        const int r = (rtb + rt2) * 16 + fkg * 4 + g;
        if (r < KA) {
          pv = fmaf(sh.m[r], fmaxf(v[g] + bgc, 0.f), pv);
        }
      }
    }
    pv += __shfl_xor(pv, 16);
    pv += __shfl_xor(pv, 32);
    if (lane < 16) sh.u.r.red[(wid >> 3) * H + col] = pv;
  }
  __syncthreads();
  if (tid < H) {
    const float invp = 1.0f / fmaxf(sh.cnt, 1.0f);
    sh.u.r.pooled[tid] = (sh.u.r.red[tid] + sh.u.r.red[H + tid]) * invp;
  }
  __syncthreads();

  // ---------------- Phase 6: latent1 = relu(pooled @ w_f1 + b_f1) ---------
  {
    const int d  = tid & (D - 1);
    const int hh = tid >> 8;               // 0..3: K=128 in quarters
    const float* wf = w_f1 + d;
    float acc = 0.f;
    const int k0 = hh * 32;
    #pragma unroll 8
    for (int k = 0; k < 32; ++k)
      acc = fmaf(sh.u.r.pooled[k0 + k], wf[(k0 + k) * D], acc);
    sh.u.r.red[hh * D + d] = acc;
  }
  __syncthreads();
  if (tid < D) {
    sh.u.r.latent1[tid] = fmaxf(sh.u.r.red[tid] + sh.u.r.red[D + tid] +
                                sh.u.r.red[2*D + tid] + sh.u.r.red[3*D + tid] +
                                b_f1[tid], 0.f);
  }
  __syncthreads();

  // ---------------- Phase 7: out = latent1 @ w_f2 + b_f2 ------------------
  {
    const int d  = tid & (D - 1);
    const int hh = tid >> 8;               // K=256 in quarters
    const float* wf = w_f2 + d;
    float acc = 0.f;
    const int k0 = hh * 64;
    #pragma unroll 8
    for (int k = 0; k < 64; ++k)
      acc = fmaf(sh.u.r.latent1[k0 + k], wf[(k0 + k) * D], acc);
    sh.u.r.red[hh * D + d] = acc;     // latent1 != red: no hazard
  }
  __syncthreads();
  if (tid < D) {
    out[(size_t)n * D + tid] = sh.u.r.red[tid] + sh.u.r.red[D + tid] +
                               sh.u.r.red[2*D + tid] + sh.u.r.red[3*D + tid] +
                               b_f2[tid];
  }
}

extern "C" void kernel_launch(void* const* d_in, const int* in_sizes, int n_in,
                              void* d_out, int out_size, void* d_ws, size_t ws_size,
                              hipStream_t stream) {
  const float* states = (const float*)d_in[0];
  const float* masks  = (const float*)d_in[1];
  const float* w_a  = (const float*)d_in[2];
  const float* b_a  = (const float*)d_in[3];
  const float* w_r1 = (const float*)d_in[4];
  const float* b_r1 = (const float*)d_in[5];
  const float* w_r2 = (const float*)d_in[6];
  const float* b_r2 = (const float*)d_in[7];
  const float* w_g  = (const float*)d_in[8];
  const float* b_g  = (const float*)d_in[9];
  const float* w_f1 = (const float*)d_in[10];
  const float* b_f1 = (const float*)d_in[11];
  const float* w_f2 = (const float*)d_in[12];
  const float* b_f2 = (const float*)d_in[13];
  float* out = (float*)d_out;
  unsigned short* wp = (unsigned short*)d_ws;

  hipLaunchKernelGGL(pack_weights, dim3((NFRAG * 64 + 255) / 256), dim3(256), 0, stream,
                     w_r1, w_r2, w_g, wp);
  hipLaunchKernelGGL(rpe_kernel, dim3(NBLK), dim3(BLOCK), 0, stream,
                     states, masks, w_a, b_a, w_r1, b_r1, b_r2,
                     b_g, w_f1, b_f1, w_f2, b_f2, wp, out);
}